// Round 9
// baseline (237.489 us; speedup 1.0000x reference)
//
#include <hip/hip_runtime.h>
#include <cstdint>
#include <cstddef>

#define NNODES 50000
#define NEDGES 800000
#define MEDGES (NEDGES + NNODES)
#define FIN    256
#define HID    96
#define NCLS   32
#define NEG_SLOPE 0.2f

#define NBUCK  391      // ceil(50000/128): 128-node dst ranges
#define BCAP   3072     // per-bucket staging capacity (mean 2176, sigma ~45)

typedef unsigned int uint32;
typedef __attribute__((ext_vector_type(8))) short short8;   // 8 bf16 = 4 VGPR
typedef __attribute__((ext_vector_type(4))) float f32x4;    // MFMA acc

__device__ __forceinline__ ushort bf_round(float f) {
    uint32 u = __float_as_uint(f);
    u += 0x7FFFu + ((u >> 16) & 1u);            // RNE
    return (ushort)(u >> 16);
}
__device__ __forceinline__ uint32 pack_bf16x2(float a, float b) {
    return (uint32)bf_round(a) | ((uint32)bf_round(b) << 16);
}
__device__ __forceinline__ float bf_lo(uint32 u) { return __uint_as_float(u << 16); }
__device__ __forceinline__ float bf_hi(uint32 u) { return __uint_as_float(u & 0xFFFF0000u); }
__device__ __forceinline__ float lrelu(float t) { return (t > 0.f) ? t : NEG_SLOPE * t; }
__device__ __forceinline__ float af(int i) { return __int_as_float(i); }

// ---------------- CSR build: bucketed two-pass sort ----------------
// staging entry packed: src (16 bits, 50000<65536) | (dst&127)<<16 -> 4B not 8B.

__global__ __launch_bounds__(256) void bucket1_kernel(const int* __restrict__ ei,
                                                      int* __restrict__ gcount,
                                                      int* __restrict__ staging) {
    __shared__ int hist[NBUCK];
    __shared__ int base_sh[NBUCK];
    for (int i = threadIdx.x; i < NBUCK; i += 256) hist[i] = 0;
    __syncthreads();

    int v[8], rk[8], bk[8];
    int e0 = blockIdx.x * 2048;
#pragma unroll
    for (int i = 0; i < 8; ++i) {
        int e = e0 + i * 256 + threadIdx.x;
        if (e < MEDGES) {
            int s, d;
            if (e < NEDGES) { s = ei[e]; d = ei[NEDGES + e]; }
            else            { s = e - NEDGES; d = s; }
            bk[i] = d >> 7;
            v[i]  = s | ((d & 127) << 16);
            rk[i] = atomicAdd(&hist[bk[i]], 1);
        } else bk[i] = -1;
    }
    __syncthreads();
    for (int i = threadIdx.x; i < NBUCK; i += 256) {
        int c = hist[i];
        base_sh[i] = c ? atomicAdd(&gcount[i], c) : 0;
    }
    __syncthreads();
#pragma unroll
    for (int i = 0; i < 8; ++i) {
        if (bk[i] >= 0) {
            int pos = base_sh[bk[i]] + rk[i];
            if (pos < BCAP)
                staging[(size_t)bk[i] * BCAP + pos] = v[i];
        }
    }
}

__global__ __launch_bounds__(512) void bscan_kernel(const int* __restrict__ gcount,
                                                    int* __restrict__ bbase) {
    __shared__ int sd[512];
    int t = threadIdx.x;
    int v = (t < NBUCK) ? gcount[t] : 0;
    sd[t] = v;
    __syncthreads();
    for (int off = 1; off < 512; off <<= 1) {
        int val = (t >= off) ? sd[t - off] : 0;
        __syncthreads();
        sd[t] += val;
        __syncthreads();
    }
    if (t < NBUCK) bbase[t] = sd[t] - v;
}

__global__ __launch_bounds__(256) void bucket2_kernel(const int* __restrict__ staging,
                                                      const int* __restrict__ gcount,
                                                      const int* __restrict__ bbase,
                                                      int* __restrict__ rowptr,
                                                      int* __restrict__ esrc) {
    __shared__ int dcount[128];
    __shared__ int dincl[128];
    __shared__ int dexcl[128];
    __shared__ int fillc[128];

    const int b     = blockIdx.x;
    const int t     = threadIdx.x;
    const int cnt   = gcount[b];
    const int ebase = bbase[b];
    const int node0 = b << 7;
    const int* st   = staging + (size_t)b * BCAP;

    for (int i = t; i < 128; i += 256) { dcount[i] = 0; fillc[i] = 0; }
    __syncthreads();

    for (int i = t; i < cnt; i += 256)
        atomicAdd(&dcount[st[i] >> 16], 1);
    __syncthreads();

    if (t < 128) dincl[t] = dcount[t];
    __syncthreads();
    for (int off = 1; off < 128; off <<= 1) {
        int val = (t >= off && t < 128) ? dincl[t - off] : 0;
        __syncthreads();
        if (t < 128) dincl[t] += val;
        __syncthreads();
    }
    if (t < 128) {
        int excl = dincl[t] - dcount[t];
        dexcl[t] = excl;
        int node = node0 + t;
        if (node < NNODES) rowptr[node] = ebase + excl;
    }
    if (b == NBUCK - 1 && t == 0) rowptr[NNODES] = MEDGES;
    __syncthreads();

    for (int i = t; i < cnt; i += 256) {
        int v = st[i];
        int dd = v >> 16;
        int r = atomicAdd(&fillc[dd], 1);
        esrc[ebase + dexcl[dd] + r] = v & 0xFFFF;
    }
}

// ---------------- W1 & W2 -> bf16 B-fragment pack ----------------

__global__ __launch_bounds__(256) void packw_kernel(const float* __restrict__ W1,
                                                    const float* __restrict__ W2,
                                                    ushort* __restrict__ W1p,
                                                    ushort* __restrict__ W2p) {
    for (int idx = threadIdx.x; idx < 6 * 8 * 64 * 8; idx += 256) {
        int j     = idx & 7;
        int lane  = (idx >> 3) & 63;
        int kstep = (idx >> 9) & 7;
        int ntile = idx >> 12;
        int k = kstep * 32 + ((lane >> 4) << 3) + j;
        int n = ntile * 16 + (lane & 15);
        W1p[idx] = bf_round(W1[(size_t)k * 96 + n]);
    }
    for (int idx = threadIdx.x; idx < 2 * 3 * 64 * 8; idx += 256) {
        int j     = idx & 7;
        int lane  = (idx >> 3) & 63;
        int kstep = (idx >> 9) % 3;
        int ntile = (idx >> 9) / 3;
        int k = kstep * 32 + ((lane >> 4) << 3) + j;
        int n = ntile * 16 + (lane & 15);
        W2p[idx] = bf_round(W2[(size_t)k * 32 + n]);
    }
}

// ---------------- GEMM1 via MFMA: h1(bf16) = x @ W1 (+ fused alpha dots) ----------------

__global__ __launch_bounds__(256) void gemm1_kernel(const float* __restrict__ x,
                                                    const ushort* __restrict__ W1p,
                                                    const float* __restrict__ a_src,
                                                    const float* __restrict__ a_dst,
                                                    ushort* __restrict__ h1,
                                                    float* __restrict__ as1,
                                                    float* __restrict__ ad1) {
    const int tid  = threadIdx.x;
    const int lane = tid & 63;
    const int wv   = tid >> 6;
    const int m    = lane & 15;
    const int quad = lane >> 4;
    const int node0 = blockIdx.x * 64;

    int arow = node0 + wv * 16 + m;
    if (arow >= NNODES) arow = NNODES - 1;
    const float* xr = x + (size_t)arow * FIN + quad * 8;

    const short8* Wp = (const short8*)W1p;

    f32x4 acc[6];
#pragma unroll
    for (int t = 0; t < 6; ++t) acc[t] = (f32x4){0.f, 0.f, 0.f, 0.f};

#pragma unroll
    for (int ks = 0; ks < 8; ++ks) {
        float4 v0 = *(const float4*)(xr + ks * 32);
        float4 v1 = *(const float4*)(xr + ks * 32 + 4);
        short8 a;
        a[0] = (short)bf_round(v0.x); a[1] = (short)bf_round(v0.y);
        a[2] = (short)bf_round(v0.z); a[3] = (short)bf_round(v0.w);
        a[4] = (short)bf_round(v1.x); a[5] = (short)bf_round(v1.y);
        a[6] = (short)bf_round(v1.z); a[7] = (short)bf_round(v1.w);
#pragma unroll
        for (int t = 0; t < 6; ++t) {
            short8 b = Wp[(t * 8 + ks) * 64 + lane];
            acc[t] = __builtin_amdgcn_mfma_f32_16x16x32_bf16(a, b, acc[t], 0, 0, 0);
        }
    }

    float as_reg[6], ad_reg[6];
#pragma unroll
    for (int t = 0; t < 6; ++t) {
        as_reg[t] = a_src[t * 16 + m];
        ad_reg[t] = a_dst[t * 16 + m];
    }

#pragma unroll
    for (int r = 0; r < 4; ++r) {
        int node = node0 + wv * 16 + quad * 4 + r;
        float ps = 0.f, pd = 0.f;
#pragma unroll
        for (int t = 0; t < 6; ++t) {
            ps += acc[t][r] * as_reg[t];
            pd += acc[t][r] * ad_reg[t];
        }
#pragma unroll
        for (int off = 1; off < 16; off <<= 1) {
            ps += __shfl_xor(ps, off);
            pd += __shfl_xor(pd, off);
        }
        if (node < NNODES) {
            ushort* hp = h1 + (size_t)node * 96 + m;
#pragma unroll
            for (int t = 0; t < 6; ++t) hp[t * 16] = bf_round(acc[t][r]);
            if (m == 0) { as1[node] = ps; ad1[node] = pd; }
        }
    }
}

// ---------------- GEMM2 via MFMA: h2(bf16 packed) = out1(bf16) @ W2 ----------------
// h2b[node*16 + m] packs (feat m, feat m+16) -> 64 B rows for agg32's gather.

__global__ __launch_bounds__(256) void gemm2_kernel(const uint32* __restrict__ y48,
                                                    const ushort* __restrict__ W2p,
                                                    const float* __restrict__ a_src,
                                                    const float* __restrict__ a_dst,
                                                    uint32* __restrict__ h2b,
                                                    float* __restrict__ as2,
                                                    float* __restrict__ ad2) {
    const int tid  = threadIdx.x;
    const int lane = tid & 63;
    const int wv   = tid >> 6;
    const int m    = lane & 15;
    const int quad = lane >> 4;
    const int node0 = blockIdx.x * 64;

    int arow = node0 + wv * 16 + m;
    if (arow >= NNODES) arow = NNODES - 1;
    const short8* Ar = (const short8*)(y48 + (size_t)arow * 48);
    const short8* Wp = (const short8*)W2p;

    f32x4 acc[2];
    acc[0] = (f32x4){0.f, 0.f, 0.f, 0.f};
    acc[1] = (f32x4){0.f, 0.f, 0.f, 0.f};

#pragma unroll
    for (int ks = 0; ks < 3; ++ks) {
        short8 a = Ar[ks * 4 + quad];
#pragma unroll
        for (int t = 0; t < 2; ++t) {
            short8 b = Wp[(t * 3 + ks) * 64 + lane];
            acc[t] = __builtin_amdgcn_mfma_f32_16x16x32_bf16(a, b, acc[t], 0, 0, 0);
        }
    }

    float as_reg[2], ad_reg[2];
#pragma unroll
    for (int t = 0; t < 2; ++t) {
        as_reg[t] = a_src[t * 16 + m];
        ad_reg[t] = a_dst[t * 16 + m];
    }

#pragma unroll
    for (int r = 0; r < 4; ++r) {
        int node = node0 + wv * 16 + quad * 4 + r;
        float ps = 0.f, pd = 0.f;
#pragma unroll
        for (int t = 0; t < 2; ++t) {
            ps += acc[t][r] * as_reg[t];
            pd += acc[t][r] * ad_reg[t];
        }
#pragma unroll
        for (int off = 1; off < 16; off <<= 1) {
            ps += __shfl_xor(ps, off);
            pd += __shfl_xor(pd, off);
        }
        if (node < NNODES) {
            h2b[(size_t)node * 16 + m] = pack_bf16x2(acc[0][r], acc[1][r]);
            if (m == 0) { as2[node] = ps; ad2[node] = pd; }
        }
    }
}

// ---------------- Fused attn + aggregation layer 1: h bf16, F=96, ELU ----------------
// Gather: 4 quad-groups x 12 active lanes, one dwordx4 row-read per group
// -> 4 edges per wave instruction (0.25 VMEM/edge). Merge via shfl_xor(16/32).

__global__ __launch_bounds__(256) void agg96_kernel(const ushort* __restrict__ h,
                                                    const float* __restrict__ asrc,
                                                    const float* __restrict__ adst,
                                                    const float* __restrict__ bias,
                                                    const int* __restrict__ rowptr,
                                                    const int* __restrict__ esrc,
                                                    uint32* __restrict__ out1b) {
    __shared__ int2 sa[4][64];
    int wave = threadIdx.x >> 6;
    int lane = threadIdx.x & 63;
    int i = blockIdx.x * 4 + wave;
    if (i >= NNODES) return;

    int start = rowptr[i], end = rowptr[i + 1];
    int deg = end - start;
    float ad = adst[i];

    if (deg <= 64) {
        // softmax: lane per edge
        int p = start + lane;
        bool valid = p < end;
        int s_reg = valid ? esrc[p] : 0;
        float e = valid ? lrelu(asrc[s_reg] + ad) : -1e30f;
        float mx = e;
#pragma unroll
        for (int off = 32; off; off >>= 1) mx = fmaxf(mx, __shfl_xor(mx, off));
        float ex = valid ? __expf(e - mx) : 0.f;
        float sum = ex;
#pragma unroll
        for (int off = 32; off; off >>= 1) sum += __shfl_xor(sum, off);
        sa[wave][lane] = make_int2(s_reg, __float_as_int(ex / sum));

        // gather: quad q handles edge eb+q; lane fl<12 reads 16B of the row
        const int q   = lane >> 4;
        const int fl  = lane & 15;
        const int flc = (fl < 12) ? fl : 11;
        float acc[8];
#pragma unroll
        for (int j = 0; j < 8; ++j) acc[j] = 0.f;

#pragma unroll 2
        for (int eb = 0; eb < deg; eb += 4) {
            int e0 = eb + q;
            int2 qq = sa[wave][(e0 < 64) ? e0 : 63];
            float a = (fl < 12 && e0 < deg) ? af(qq.y) : 0.f;
            const uint4* hr = (const uint4*)(h + (size_t)qq.x * 96);
            uint4 u = hr[flc];
            acc[0] = fmaf(a, bf_lo(u.x), acc[0]);
            acc[1] = fmaf(a, bf_hi(u.x), acc[1]);
            acc[2] = fmaf(a, bf_lo(u.y), acc[2]);
            acc[3] = fmaf(a, bf_hi(u.y), acc[3]);
            acc[4] = fmaf(a, bf_lo(u.z), acc[4]);
            acc[5] = fmaf(a, bf_hi(u.z), acc[5]);
            acc[6] = fmaf(a, bf_lo(u.w), acc[6]);
            acc[7] = fmaf(a, bf_hi(u.w), acc[7]);
        }
#pragma unroll
        for (int j = 0; j < 8; ++j) {
            acc[j] += __shfl_xor(acc[j], 16);
            acc[j] += __shfl_xor(acc[j], 32);
        }
        if (lane < 12) {
            float v[8];
#pragma unroll
            for (int j = 0; j < 8; ++j) {
                float t = acc[j] + bias[8 * lane + j];
                v[j] = (t > 0.f) ? t : expm1f(t);
            }
            uint4 o;
            o.x = pack_bf16x2(v[0], v[1]);
            o.y = pack_bf16x2(v[2], v[3]);
            o.z = pack_bf16x2(v[4], v[5]);
            o.w = pack_bf16x2(v[6], v[7]);
            *(uint4*)(out1b + (size_t)i * 48 + 4 * lane) = o;
        }
    } else {
        // fallback (deg>64): scalar per edge, self-contained
        int fl47 = (lane < 48) ? lane : 47;
        float mx = -1e30f;
        for (int p = start + lane; p < end; p += 64)
            mx = fmaxf(mx, lrelu(asrc[esrc[p]] + ad));
#pragma unroll
        for (int off = 32; off; off >>= 1) mx = fmaxf(mx, __shfl_xor(mx, off));
        float sum = 0.f;
        for (int p = start + lane; p < end; p += 64)
            sum += __expf(lrelu(asrc[esrc[p]] + ad) - mx);
#pragma unroll
        for (int off = 32; off; off >>= 1) sum += __shfl_xor(sum, off);
        float inv = 1.f / sum;
        float acc0 = 0.f, acc1 = 0.f;
        for (int p = start; p < end; ++p) {
            int s = esrc[p];
            float a = __expf(lrelu(asrc[s] + ad) - mx) * inv;
            uint32 u = ((const uint32*)(h + (size_t)s * 96))[fl47];
            acc0 += a * bf_lo(u);
            acc1 += a * bf_hi(u);
        }
        if (lane < 48) {
            float v0 = acc0 + bias[2 * lane];
            v0 = (v0 > 0.f) ? v0 : expm1f(v0);
            float v1 = acc1 + bias[2 * lane + 1];
            v1 = (v1 > 0.f) ? v1 : expm1f(v1);
            out1b[(size_t)i * 48 + lane] = pack_bf16x2(v0, v1);
        }
    }
}

// ---------------- Fused attn + aggregation layer 2: h2 bf16 packed, log_softmax ----------------
// 8 groups of 8 lanes; each group reads a 64 B row via dwordx2 -> 8 edges/iter.
// h2b uint32 index m holds feats (m, m+16).

__global__ __launch_bounds__(256) void agg32_kernel(const uint32* __restrict__ h2b,
                                                    const float* __restrict__ asrc,
                                                    const float* __restrict__ adst,
                                                    const float* __restrict__ bias,
                                                    const int* __restrict__ rowptr,
                                                    const int* __restrict__ esrc,
                                                    float* __restrict__ out) {
    __shared__ int2 sa[4][64];
    int wave = threadIdx.x >> 6;
    int lane = threadIdx.x & 63;
    int i = blockIdx.x * 4 + wave;
    if (i >= NNODES) return;

    int start = rowptr[i], end = rowptr[i + 1];
    int deg = end - start;
    float ad = adst[i];

    if (deg <= 64) {
        int p = start + lane;
        bool valid = p < end;
        int s_reg = valid ? esrc[p] : 0;
        float e = valid ? lrelu(asrc[s_reg] + ad) : -1e30f;
        float mx = e;
#pragma unroll
        for (int off = 32; off; off >>= 1) mx = fmaxf(mx, __shfl_xor(mx, off));
        float ex = valid ? __expf(e - mx) : 0.f;
        float sum = ex;
#pragma unroll
        for (int off = 32; off; off >>= 1) sum += __shfl_xor(sum, off);
        sa[wave][lane] = make_int2(s_reg, __float_as_int(ex / sum));

        const int g  = lane >> 3;        // edge subgroup 0..7
        const int fl = lane & 7;         // uint2 index within row
        float acc[4];
#pragma unroll
        for (int j = 0; j < 4; ++j) acc[j] = 0.f;

#pragma unroll 2
        for (int eb = 0; eb < deg; eb += 8) {
            int e0 = eb + g;
            int2 qq = sa[wave][(e0 < 64) ? e0 : 63];
            float a = (e0 < deg) ? af(qq.y) : 0.f;
            const uint2* hr = (const uint2*)(h2b + (size_t)qq.x * 16);
            uint2 u = hr[fl];
            acc[0] = fmaf(a, bf_lo(u.x), acc[0]);   // feat 2fl
            acc[1] = fmaf(a, bf_hi(u.x), acc[1]);   // feat 2fl+16
            acc[2] = fmaf(a, bf_lo(u.y), acc[2]);   // feat 2fl+1
            acc[3] = fmaf(a, bf_hi(u.y), acc[3]);   // feat 2fl+17
        }
#pragma unroll
        for (int j = 0; j < 4; ++j) {
            acc[j] += __shfl_xor(acc[j], 8);
            acc[j] += __shfl_xor(acc[j], 16);
            acc[j] += __shfl_xor(acc[j], 32);
        }

        float z0 = acc[0] + bias[2 * fl];
        float z1 = acc[1] + bias[2 * fl + 16];
        float z2 = acc[2] + bias[2 * fl + 1];
        float z3 = acc[3] + bias[2 * fl + 17];
        float m2 = fmaxf(fmaxf(z0, z1), fmaxf(z2, z3));
#pragma unroll
        for (int off = 4; off; off >>= 1) m2 = fmaxf(m2, __shfl_xor(m2, off));
        float s2 = __expf(z0 - m2) + __expf(z1 - m2) + __expf(z2 - m2) + __expf(z3 - m2);
#pragma unroll
        for (int off = 4; off; off >>= 1) s2 += __shfl_xor(s2, off);
        float ls = m2 + logf(s2);
        if (lane < 8) {
            float* op = out + (size_t)i * 32;
            op[2 * fl]      = z0 - ls;
            op[2 * fl + 16] = z1 - ls;
            op[2 * fl + 1]  = z2 - ls;
            op[2 * fl + 17] = z3 - ls;
        }
    } else {
        // fallback (deg>64): halves, scalar, packed-layout aware
        int e2 = lane >> 5;
        int f  = lane & 31;
        float mx = -1e30f;
        for (int p = start + lane; p < end; p += 64)
            mx = fmaxf(mx, lrelu(asrc[esrc[p]] + ad));
#pragma unroll
        for (int off = 32; off; off >>= 1) mx = fmaxf(mx, __shfl_xor(mx, off));
        float sum = 0.f;
        for (int p = start + lane; p < end; p += 64)
            sum += __expf(lrelu(asrc[esrc[p]] + ad) - mx);
#pragma unroll
        for (int off = 32; off; off >>= 1) sum += __shfl_xor(sum, off);
        float inv = 1.f / sum;
        float acc = 0.f;
        for (int p = start + e2; p < end; p += 2) {
            int s = esrc[p];
            float a = __expf(lrelu(asrc[s] + ad) - mx) * inv;
            uint32 u = h2b[(size_t)s * 16 + (f & 15)];
            acc += a * ((f < 16) ? bf_lo(u) : bf_hi(u));
        }
        acc += __shfl_xor(acc, 32);

        float z = acc + bias[f];
        float m2 = z;
#pragma unroll
        for (int off = 16; off; off >>= 1) m2 = fmaxf(m2, __shfl_xor(m2, off));
        float ex2 = __expf(z - m2);
        float s2 = ex2;
#pragma unroll
        for (int off = 16; off; off >>= 1) s2 += __shfl_xor(s2, off);
        if (lane < 32) out[(size_t)i * 32 + f] = z - m2 - logf(s2);
    }
}

// ---------------- launch ----------------

extern "C" void kernel_launch(void* const* d_in, const int* in_sizes, int n_in,
                              void* d_out, int out_size, void* d_ws, size_t ws_size,
                              hipStream_t stream) {
    const float* x   = (const float*)d_in[0];
    const int*   ei  = (const int*)d_in[1];
    const float* W1  = (const float*)d_in[2];
    const float* a1s = (const float*)d_in[3];
    const float* a1d = (const float*)d_in[4];
    const float* b1  = (const float*)d_in[5];
    const float* W2  = (const float*)d_in[6];
    const float* a2s = (const float*)d_in[7];
    const float* a2d = (const float*)d_in[8];
    const float* b2  = (const float*)d_in[9];
    float* out = (float*)d_out;

    size_t off = 0;
    auto alloc = [&](size_t bytes) {
        void* p = (char*)d_ws + off;
        off += (bytes + 255) & ~(size_t)255;
        return p;
    };
    ushort* h1    = (ushort*)alloc((size_t)NNODES * HID * 2);   // bf16, 9.6 MB
    uint32* out1b = (uint32*)alloc((size_t)NNODES * 48 * 4);    // bf16x2, 9.6 MB
    int*  staging = (int*)alloc((size_t)NBUCK * BCAP * 4);      // 4.8 MB
    float* as1    = (float*)alloc((size_t)NNODES * 4);
    float* ad1    = (float*)alloc((size_t)NNODES * 4);
    float* as2    = (float*)alloc((size_t)NNODES * 4);
    float* ad2    = (float*)alloc((size_t)NNODES * 4);
    int*   rowptr = (int*)alloc((size_t)(NNODES + 1) * 4);
    int*   esrc   = (int*)alloc((size_t)MEDGES * 4);
    ushort* W1p   = (ushort*)alloc((size_t)6 * 8 * 64 * 8 * 2); // 48 KiB
    ushort* W2p   = (ushort*)alloc((size_t)2 * 3 * 64 * 8 * 2); // 6 KiB
    int*   gcount = (int*)alloc((size_t)NBUCK * 4);
    int*   bbase  = (int*)alloc((size_t)NBUCK * 4);
    uint32* h2b   = (uint32*)h1;  // h1 dead after agg96; 3.2 MB fits in 9.6 MB

    hipMemsetAsync(gcount, 0, (size_t)NBUCK * 4, stream);

    const int nbB1   = (MEDGES + 2047) / 2048;  // 416
    const int nbGemm = (NNODES + 63) / 64;      // 782
    const int nbAgg  = (NNODES + 3) / 4;        // 12500

    packw_kernel<<<1, 256, 0, stream>>>(W1, W2, W1p, W2p);
    bucket1_kernel<<<nbB1, 256, 0, stream>>>(ei, gcount, staging);
    bscan_kernel<<<1, 512, 0, stream>>>(gcount, bbase);
    bucket2_kernel<<<NBUCK, 256, 0, stream>>>(staging, gcount, bbase, rowptr, esrc);

    // layer 1
    gemm1_kernel<<<nbGemm, 256, 0, stream>>>(x, W1p, a1s, a1d, h1, as1, ad1);
    agg96_kernel<<<nbAgg, 256, 0, stream>>>(h1, as1, ad1, b1, rowptr, esrc, out1b);

    // layer 2
    gemm2_kernel<<<nbGemm, 256, 0, stream>>>(out1b, W2p, a2s, a2d, h2b, as2, ad2);
    agg32_kernel<<<nbAgg, 256, 0, stream>>>(h2b, as2, ad2, b2, rowptr, esrc, out);
}

// Round 10
// 215.065 us; speedup vs baseline: 1.1043x; 1.1043x over previous
//
#include <hip/hip_runtime.h>
#include <cstdint>
#include <cstddef>

#define NNODES 50000
#define NEDGES 800000
#define MEDGES (NEDGES + NNODES)
#define FIN    256
#define HID    96
#define NCLS   32
#define NEG_SLOPE 0.2f

#define NBUCK  391      // ceil(50000/128): 128-node dst ranges
#define BCAP   3072     // per-bucket staging capacity (mean 2176, sigma ~45)

typedef unsigned int uint32;
typedef __attribute__((ext_vector_type(8))) short short8;   // 8 bf16 = 4 VGPR
typedef __attribute__((ext_vector_type(4))) float f32x4;    // MFMA acc

__device__ __forceinline__ ushort bf_round(float f) {
    uint32 u = __float_as_uint(f);
    u += 0x7FFFu + ((u >> 16) & 1u);            // RNE
    return (ushort)(u >> 16);
}
__device__ __forceinline__ uint32 pack_bf16x2(float a, float b) {
    return (uint32)bf_round(a) | ((uint32)bf_round(b) << 16);
}
__device__ __forceinline__ float bf_lo(uint32 u) { return __uint_as_float(u << 16); }
__device__ __forceinline__ float bf_hi(uint32 u) { return __uint_as_float(u & 0xFFFF0000u); }
__device__ __forceinline__ float lrelu(float t) { return (t > 0.f) ? t : NEG_SLOPE * t; }
__device__ __forceinline__ float af(int i) { return __int_as_float(i); }
__device__ __forceinline__ float elu_fast(float t) { return (t > 0.f) ? t : (__expf(t) - 1.f); }

// ---------------- CSR build: bucketed two-pass sort ----------------
// staging entry packed: src (16 bits, 50000<65536) | (dst&127)<<16.

__global__ __launch_bounds__(256) void bucket1_kernel(const int* __restrict__ ei,
                                                      int* __restrict__ gcount,
                                                      int* __restrict__ staging) {
    __shared__ int hist[NBUCK];
    __shared__ int base_sh[NBUCK];
    for (int i = threadIdx.x; i < NBUCK; i += 256) hist[i] = 0;
    __syncthreads();

    int v[8], rk[8], bk[8];
    int e0 = blockIdx.x * 2048;
#pragma unroll
    for (int i = 0; i < 8; ++i) {
        int e = e0 + i * 256 + threadIdx.x;
        if (e < MEDGES) {
            int s, d;
            if (e < NEDGES) { s = ei[e]; d = ei[NEDGES + e]; }
            else            { s = e - NEDGES; d = s; }
            bk[i] = d >> 7;
            v[i]  = s | ((d & 127) << 16);
            rk[i] = atomicAdd(&hist[bk[i]], 1);
        } else bk[i] = -1;
    }
    __syncthreads();
    for (int i = threadIdx.x; i < NBUCK; i += 256) {
        int c = hist[i];
        base_sh[i] = c ? atomicAdd(&gcount[i], c) : 0;
    }
    __syncthreads();
#pragma unroll
    for (int i = 0; i < 8; ++i) {
        if (bk[i] >= 0) {
            int pos = base_sh[bk[i]] + rk[i];
            if (pos < BCAP)
                staging[(size_t)bk[i] * BCAP + pos] = v[i];
        }
    }
}

// One block per bucket. Self-scans gcount for its edge-space base (replaces the
// separate bscan kernel), builds rowptr via LDS scan, writes esrc contiguously.
__global__ __launch_bounds__(256) void bucket2_kernel(const int* __restrict__ staging,
                                                      const int* __restrict__ gcount,
                                                      int* __restrict__ rowptr,
                                                      int* __restrict__ esrc) {
    __shared__ int dcount[128];
    __shared__ int dincl[128];
    __shared__ int dexcl[128];
    __shared__ int fillc[128];
    __shared__ int red_s[256];

    const int b = blockIdx.x;
    const int t = threadIdx.x;

    // prefix: ebase = sum gcount[0..b-1]
    int pv = 0;
    for (int idx = t; idx < b; idx += 256) pv += gcount[idx];
    red_s[t] = pv;
    __syncthreads();
    for (int off2 = 128; off2; off2 >>= 1) {
        if (t < off2) red_s[t] += red_s[t + off2];
        __syncthreads();
    }
    const int ebase = red_s[0];
    const int cnt   = gcount[b];
    const int node0 = b << 7;
    const int* st   = staging + (size_t)b * BCAP;

    for (int i = t; i < 128; i += 256) { dcount[i] = 0; fillc[i] = 0; }
    __syncthreads();

    for (int i = t; i < cnt; i += 256)
        atomicAdd(&dcount[st[i] >> 16], 1);
    __syncthreads();

    if (t < 128) dincl[t] = dcount[t];
    __syncthreads();
    for (int off = 1; off < 128; off <<= 1) {
        int val = (t >= off && t < 128) ? dincl[t - off] : 0;
        __syncthreads();
        if (t < 128) dincl[t] += val;
        __syncthreads();
    }
    if (t < 128) {
        int excl = dincl[t] - dcount[t];
        dexcl[t] = excl;
        int node = node0 + t;
        if (node < NNODES) rowptr[node] = ebase + excl;
    }
    if (b == NBUCK - 1 && t == 0) rowptr[NNODES] = MEDGES;
    __syncthreads();

    for (int i = t; i < cnt; i += 256) {
        int v = st[i];
        int dd = v >> 16;
        int r = atomicAdd(&fillc[dd], 1);
        esrc[ebase + dexcl[dd] + r] = v & 0xFFFF;
    }
}

// ---------------- W1 & W2 -> bf16 B-fragment pack (grid-stride, 13 blocks) ----------------

__global__ __launch_bounds__(256) void packw_kernel(const float* __restrict__ W1,
                                                    const float* __restrict__ W2,
                                                    ushort* __restrict__ W1p,
                                                    ushort* __restrict__ W2p) {
    int stride = gridDim.x * 256;
    for (int idx = blockIdx.x * 256 + threadIdx.x; idx < 6 * 8 * 64 * 8; idx += stride) {
        int j     = idx & 7;
        int lane  = (idx >> 3) & 63;
        int kstep = (idx >> 9) & 7;
        int ntile = idx >> 12;
        int k = kstep * 32 + ((lane >> 4) << 3) + j;
        int n = ntile * 16 + (lane & 15);
        W1p[idx] = bf_round(W1[(size_t)k * 96 + n]);
    }
    for (int idx = blockIdx.x * 256 + threadIdx.x; idx < 2 * 3 * 64 * 8; idx += stride) {
        int j     = idx & 7;
        int lane  = (idx >> 3) & 63;
        int kstep = (idx >> 9) % 3;
        int ntile = (idx >> 9) / 3;
        int k = kstep * 32 + ((lane >> 4) << 3) + j;
        int n = ntile * 16 + (lane & 15);
        W2p[idx] = bf_round(W2[(size_t)k * 32 + n]);
    }
}

// ---------------- GEMM1 via MFMA: h1(bf16) = x @ W1 (+ fused alpha dots) ----------------

__global__ __launch_bounds__(256) void gemm1_kernel(const float* __restrict__ x,
                                                    const ushort* __restrict__ W1p,
                                                    const float* __restrict__ a_src,
                                                    const float* __restrict__ a_dst,
                                                    ushort* __restrict__ h1,
                                                    float* __restrict__ as1,
                                                    float* __restrict__ ad1) {
    const int tid  = threadIdx.x;
    const int lane = tid & 63;
    const int wv   = tid >> 6;
    const int m    = lane & 15;
    const int quad = lane >> 4;
    const int node0 = blockIdx.x * 64;

    int arow = node0 + wv * 16 + m;
    if (arow >= NNODES) arow = NNODES - 1;
    const float* xr = x + (size_t)arow * FIN + quad * 8;

    const short8* Wp = (const short8*)W1p;

    f32x4 acc[6];
#pragma unroll
    for (int t = 0; t < 6; ++t) acc[t] = (f32x4){0.f, 0.f, 0.f, 0.f};

#pragma unroll
    for (int ks = 0; ks < 8; ++ks) {
        float4 v0 = *(const float4*)(xr + ks * 32);
        float4 v1 = *(const float4*)(xr + ks * 32 + 4);
        short8 a;
        a[0] = (short)bf_round(v0.x); a[1] = (short)bf_round(v0.y);
        a[2] = (short)bf_round(v0.z); a[3] = (short)bf_round(v0.w);
        a[4] = (short)bf_round(v1.x); a[5] = (short)bf_round(v1.y);
        a[6] = (short)bf_round(v1.z); a[7] = (short)bf_round(v1.w);
#pragma unroll
        for (int t = 0; t < 6; ++t) {
            short8 b = Wp[(t * 8 + ks) * 64 + lane];
            acc[t] = __builtin_amdgcn_mfma_f32_16x16x32_bf16(a, b, acc[t], 0, 0, 0);
        }
    }

    float as_reg[6], ad_reg[6];
#pragma unroll
    for (int t = 0; t < 6; ++t) {
        as_reg[t] = a_src[t * 16 + m];
        ad_reg[t] = a_dst[t * 16 + m];
    }

#pragma unroll
    for (int r = 0; r < 4; ++r) {
        int node = node0 + wv * 16 + quad * 4 + r;
        float ps = 0.f, pd = 0.f;
#pragma unroll
        for (int t = 0; t < 6; ++t) {
            ps += acc[t][r] * as_reg[t];
            pd += acc[t][r] * ad_reg[t];
        }
#pragma unroll
        for (int off = 1; off < 16; off <<= 1) {
            ps += __shfl_xor(ps, off);
            pd += __shfl_xor(pd, off);
        }
        if (node < NNODES) {
            ushort* hp = h1 + (size_t)node * 96 + m;
#pragma unroll
            for (int t = 0; t < 6; ++t) hp[t * 16] = bf_round(acc[t][r]);
            if (m == 0) { as1[node] = ps; ad1[node] = pd; }
        }
    }
}

// ---------------- GEMM2 via MFMA: h2(bf16 packed) = out1(bf16) @ W2 ----------------
// h2b[node*16 + m] packs (feat m, feat m+16) -> 64 B rows for agg32's gather.

__global__ __launch_bounds__(256) void gemm2_kernel(const uint32* __restrict__ y48,
                                                    const ushort* __restrict__ W2p,
                                                    const float* __restrict__ a_src,
                                                    const float* __restrict__ a_dst,
                                                    uint32* __restrict__ h2b,
                                                    float* __restrict__ as2,
                                                    float* __restrict__ ad2) {
    const int tid  = threadIdx.x;
    const int lane = tid & 63;
    const int wv   = tid >> 6;
    const int m    = lane & 15;
    const int quad = lane >> 4;
    const int node0 = blockIdx.x * 64;

    int arow = node0 + wv * 16 + m;
    if (arow >= NNODES) arow = NNODES - 1;
    const short8* Ar = (const short8*)(y48 + (size_t)arow * 48);
    const short8* Wp = (const short8*)W2p;

    f32x4 acc[2];
    acc[0] = (f32x4){0.f, 0.f, 0.f, 0.f};
    acc[1] = (f32x4){0.f, 0.f, 0.f, 0.f};

#pragma unroll
    for (int ks = 0; ks < 3; ++ks) {
        short8 a = Ar[ks * 4 + quad];
#pragma unroll
        for (int t = 0; t < 2; ++t) {
            short8 b = Wp[(t * 3 + ks) * 64 + lane];
            acc[t] = __builtin_amdgcn_mfma_f32_16x16x32_bf16(a, b, acc[t], 0, 0, 0);
        }
    }

    float as_reg[2], ad_reg[2];
#pragma unroll
    for (int t = 0; t < 2; ++t) {
        as_reg[t] = a_src[t * 16 + m];
        ad_reg[t] = a_dst[t * 16 + m];
    }

#pragma unroll
    for (int r = 0; r < 4; ++r) {
        int node = node0 + wv * 16 + quad * 4 + r;
        float ps = 0.f, pd = 0.f;
#pragma unroll
        for (int t = 0; t < 2; ++t) {
            ps += acc[t][r] * as_reg[t];
            pd += acc[t][r] * ad_reg[t];
        }
#pragma unroll
        for (int off = 1; off < 16; off <<= 1) {
            ps += __shfl_xor(ps, off);
            pd += __shfl_xor(pd, off);
        }
        if (node < NNODES) {
            h2b[(size_t)node * 16 + m] = pack_bf16x2(acc[0][r], acc[1][r]);
            if (m == 0) { as2[node] = ps; ad2[node] = pd; }
        }
    }
}

// ---------------- Fused attn + aggregation layer 1: TWO nodes per wave ----------------
// Half-wave (32 lanes) per node: 24 active lanes x uint2 (8B) = 192B row, lane owns
// 4 feats (no epilogue reduction). One instruction stream drives 2 edge streams ->
// 16 gathers in flight (R8's single-stream 8 was the latency bottleneck).
// Edge slots beyond deg carry alpha=0 (padding gathers hit the hot row-0 line).

__global__ __launch_bounds__(256) void agg96_kernel(const ushort* __restrict__ h,
                                                    const float* __restrict__ asrc,
                                                    const float* __restrict__ adst,
                                                    const float* __restrict__ bias,
                                                    const int* __restrict__ rowptr,
                                                    const int* __restrict__ esrc,
                                                    uint32* __restrict__ out1b) {
    __shared__ int2 sa[4][2][32];
    const int wave = threadIdx.x >> 6;
    const int lane = threadIdx.x & 63;
    const int hf   = lane >> 5;          // node within pair
    const int fl32 = lane & 31;
    const int i = blockIdx.x * 8 + wave * 2 + hf;   // 50000 = 8*6250 exact

    const int start = rowptr[i];
    const int deg   = rowptr[i + 1] - start;
    const float ad  = adst[i];
    const int fl    = (fl32 < 24) ? fl32 : 23;

    float acc0 = 0.f, acc1 = 0.f, acc2 = 0.f, acc3 = 0.f;

    if (deg <= 32) {
        // softmax within the 32-lane half
        bool valid = fl32 < deg;
        int s_reg = valid ? esrc[start + fl32] : 0;
        float e = valid ? lrelu(asrc[s_reg] + ad) : -1e30f;
        float mx = e;
#pragma unroll
        for (int off = 16; off; off >>= 1) mx = fmaxf(mx, __shfl_xor(mx, off));
        float ex = valid ? __expf(e - mx) : 0.f;
        float sum = ex;
#pragma unroll
        for (int off = 16; off; off >>= 1) sum += __shfl_xor(sum, off);
        sa[wave][hf][fl32] = make_int2(s_reg, __float_as_int(ex / sum));

        const int4* sap = (const int4*)&sa[wave][hf][0];   // 16 int4 = 32 (s,a)

        for (int eb = 0; eb < deg; eb += 8) {
            int4 qa = sap[(eb >> 1) + 0];
            int4 qb = sap[(eb >> 1) + 1];
            int4 qc = sap[(eb >> 1) + 2];
            int4 qd = sap[(eb >> 1) + 3];
            const uint2* r0 = (const uint2*)(h + (size_t)qa.x * 96);
            const uint2* r1 = (const uint2*)(h + (size_t)qa.z * 96);
            const uint2* r2 = (const uint2*)(h + (size_t)qb.x * 96);
            const uint2* r3 = (const uint2*)(h + (size_t)qb.z * 96);
            const uint2* r4 = (const uint2*)(h + (size_t)qc.x * 96);
            const uint2* r5 = (const uint2*)(h + (size_t)qc.z * 96);
            const uint2* r6 = (const uint2*)(h + (size_t)qd.x * 96);
            const uint2* r7 = (const uint2*)(h + (size_t)qd.z * 96);
            uint2 u0 = r0[fl], u1 = r1[fl], u2 = r2[fl], u3 = r3[fl];
            uint2 u4 = r4[fl], u5 = r5[fl], u6 = r6[fl], u7 = r7[fl];
            float a0 = af(qa.y), a1 = af(qa.w), a2 = af(qb.y), a3 = af(qb.w);
            float a4 = af(qc.y), a5 = af(qc.w), a6 = af(qd.y), a7 = af(qd.w);
            acc0 += a0 * bf_lo(u0.x) + a1 * bf_lo(u1.x) + a2 * bf_lo(u2.x) + a3 * bf_lo(u3.x)
                  + a4 * bf_lo(u4.x) + a5 * bf_lo(u5.x) + a6 * bf_lo(u6.x) + a7 * bf_lo(u7.x);
            acc1 += a0 * bf_hi(u0.x) + a1 * bf_hi(u1.x) + a2 * bf_hi(u2.x) + a3 * bf_hi(u3.x)
                  + a4 * bf_hi(u4.x) + a5 * bf_hi(u5.x) + a6 * bf_hi(u6.x) + a7 * bf_hi(u7.x);
            acc2 += a0 * bf_lo(u0.y) + a1 * bf_lo(u1.y) + a2 * bf_lo(u2.y) + a3 * bf_lo(u3.y)
                  + a4 * bf_lo(u4.y) + a5 * bf_lo(u5.y) + a6 * bf_lo(u6.y) + a7 * bf_lo(u7.y);
            acc3 += a0 * bf_hi(u0.y) + a1 * bf_hi(u1.y) + a2 * bf_hi(u2.y) + a3 * bf_hi(u3.y)
                  + a4 * bf_hi(u4.y) + a5 * bf_hi(u5.y) + a6 * bf_hi(u6.y) + a7 * bf_hi(u7.y);
        }
    } else {
        // fallback deg>32 (rare): strided softmax, sequential gather, same lanes
        float mx = -1e30f;
        for (int p = start + fl32; p < start + deg; p += 32)
            mx = fmaxf(mx, lrelu(asrc[esrc[p]] + ad));
#pragma unroll
        for (int off = 16; off; off >>= 1) mx = fmaxf(mx, __shfl_xor(mx, off));
        float sum = 0.f;
        for (int p = start + fl32; p < start + deg; p += 32)
            sum += __expf(lrelu(asrc[esrc[p]] + ad) - mx);
#pragma unroll
        for (int off = 16; off; off >>= 1) sum += __shfl_xor(sum, off);
        float inv = 1.f / sum;
        for (int e = 0; e < deg; ++e) {
            int s = esrc[start + e];
            float a = __expf(lrelu(asrc[s] + ad) - mx) * inv;
            uint2 u = ((const uint2*)(h + (size_t)s * 96))[fl];
            acc0 += a * bf_lo(u.x);
            acc1 += a * bf_hi(u.x);
            acc2 += a * bf_lo(u.y);
            acc3 += a * bf_hi(u.y);
        }
    }

    if (fl32 < 24) {
        float v0 = elu_fast(acc0 + bias[4 * fl32 + 0]);
        float v1 = elu_fast(acc1 + bias[4 * fl32 + 1]);
        float v2 = elu_fast(acc2 + bias[4 * fl32 + 2]);
        float v3 = elu_fast(acc3 + bias[4 * fl32 + 3]);
        uint2 o;
        o.x = pack_bf16x2(v0, v1);
        o.y = pack_bf16x2(v2, v3);
        *(uint2*)(out1b + (size_t)i * 48 + 2 * fl32) = o;
    }
}

// ---------------- Fused attn + aggregation layer 2: h2 bf16 packed, log_softmax ----------------
// 8 groups of 8 lanes; each group reads a 64 B row via dwordx2 -> 8 edges/iter.

__global__ __launch_bounds__(256) void agg32_kernel(const uint32* __restrict__ h2b,
                                                    const float* __restrict__ asrc,
                                                    const float* __restrict__ adst,
                                                    const float* __restrict__ bias,
                                                    const int* __restrict__ rowptr,
                                                    const int* __restrict__ esrc,
                                                    float* __restrict__ out) {
    __shared__ int2 sa[4][64];
    int wave = threadIdx.x >> 6;
    int lane = threadIdx.x & 63;
    int i = blockIdx.x * 4 + wave;
    if (i >= NNODES) return;

    int start = rowptr[i], end = rowptr[i + 1];
    int deg = end - start;
    float ad = adst[i];

    if (deg <= 64) {
        int p = start + lane;
        bool valid = p < end;
        int s_reg = valid ? esrc[p] : 0;
        float e = valid ? lrelu(asrc[s_reg] + ad) : -1e30f;
        float mx = e;
#pragma unroll
        for (int off = 32; off; off >>= 1) mx = fmaxf(mx, __shfl_xor(mx, off));
        float ex = valid ? __expf(e - mx) : 0.f;
        float sum = ex;
#pragma unroll
        for (int off = 32; off; off >>= 1) sum += __shfl_xor(sum, off);
        sa[wave][lane] = make_int2(s_reg, __float_as_int(ex / sum));

        const int g  = lane >> 3;        // edge subgroup 0..7
        const int fl = lane & 7;         // uint2 index within row
        float acc[4];
#pragma unroll
        for (int j = 0; j < 4; ++j) acc[j] = 0.f;

#pragma unroll 2
        for (int eb = 0; eb < deg; eb += 8) {
            int e0 = eb + g;
            int2 qq = sa[wave][(e0 < 64) ? e0 : 63];
            float a = (e0 < deg) ? af(qq.y) : 0.f;
            const uint2* hr = (const uint2*)(h2b + (size_t)qq.x * 16);
            uint2 u = hr[fl];
            acc[0] = fmaf(a, bf_lo(u.x), acc[0]);   // feat 2fl
            acc[1] = fmaf(a, bf_hi(u.x), acc[1]);   // feat 2fl+16
            acc[2] = fmaf(a, bf_lo(u.y), acc[2]);   // feat 2fl+1
            acc[3] = fmaf(a, bf_hi(u.y), acc[3]);   // feat 2fl+17
        }
#pragma unroll
        for (int j = 0; j < 4; ++j) {
            acc[j] += __shfl_xor(acc[j], 8);
            acc[j] += __shfl_xor(acc[j], 16);
            acc[j] += __shfl_xor(acc[j], 32);
        }

        float z0 = acc[0] + bias[2 * fl];
        float z1 = acc[1] + bias[2 * fl + 16];
        float z2 = acc[2] + bias[2 * fl + 1];
        float z3 = acc[3] + bias[2 * fl + 17];
        float m2 = fmaxf(fmaxf(z0, z1), fmaxf(z2, z3));
#pragma unroll
        for (int off = 4; off; off >>= 1) m2 = fmaxf(m2, __shfl_xor(m2, off));
        float s2 = __expf(z0 - m2) + __expf(z1 - m2) + __expf(z2 - m2) + __expf(z3 - m2);
#pragma unroll
        for (int off = 4; off; off >>= 1) s2 += __shfl_xor(s2, off);
        float ls = m2 + __logf(s2);
        if (lane < 8) {
            float* op = out + (size_t)i * 32;
            op[2 * fl]      = z0 - ls;
            op[2 * fl + 16] = z1 - ls;
            op[2 * fl + 1]  = z2 - ls;
            op[2 * fl + 17] = z3 - ls;
        }
    } else {
        int e2 = lane >> 5;
        int f  = lane & 31;
        float mx = -1e30f;
        for (int p = start + lane; p < end; p += 64)
            mx = fmaxf(mx, lrelu(asrc[esrc[p]] + ad));
#pragma unroll
        for (int off = 32; off; off >>= 1) mx = fmaxf(mx, __shfl_xor(mx, off));
        float sum = 0.f;
        for (int p = start + lane; p < end; p += 64)
            sum += __expf(lrelu(asrc[esrc[p]] + ad) - mx);
#pragma unroll
        for (int off = 32; off; off >>= 1) sum += __shfl_xor(sum, off);
        float inv = 1.f / sum;
        float acc = 0.f;
        for (int p = start + e2; p < end; p += 2) {
            int s = esrc[p];
            float a = __expf(lrelu(asrc[s] + ad) - mx) * inv;
            uint32 u = h2b[(size_t)s * 16 + (f & 15)];
            acc += a * ((f < 16) ? bf_lo(u) : bf_hi(u));
        }
        acc += __shfl_xor(acc, 32);

        float z = acc + bias[f];
        float m2 = z;
#pragma unroll
        for (int off = 16; off; off >>= 1) m2 = fmaxf(m2, __shfl_xor(m2, off));
        float ex2 = __expf(z - m2);
        float s2 = ex2;
#pragma unroll
        for (int off = 16; off; off >>= 1) s2 += __shfl_xor(s2, off);
        if (lane < 32) out[(size_t)i * 32 + f] = z - m2 - __logf(s2);
    }
}

// ---------------- launch ----------------

extern "C" void kernel_launch(void* const* d_in, const int* in_sizes, int n_in,
                              void* d_out, int out_size, void* d_ws, size_t ws_size,
                              hipStream_t stream) {
    const float* x   = (const float*)d_in[0];
    const int*   ei  = (const int*)d_in[1];
    const float* W1  = (const float*)d_in[2];
    const float* a1s = (const float*)d_in[3];
    const float* a1d = (const float*)d_in[4];
    const float* b1  = (const float*)d_in[5];
    const float* W2  = (const float*)d_in[6];
    const float* a2s = (const float*)d_in[7];
    const float* a2d = (const float*)d_in[8];
    const float* b2  = (const float*)d_in[9];
    float* out = (float*)d_out;

    size_t off = 0;
    auto alloc = [&](size_t bytes) {
        void* p = (char*)d_ws + off;
        off += (bytes + 255) & ~(size_t)255;
        return p;
    };
    ushort* h1    = (ushort*)alloc((size_t)NNODES * HID * 2);   // bf16, 9.6 MB
    uint32* out1b = (uint32*)alloc((size_t)NNODES * 48 * 4);    // bf16x2, 9.6 MB
    int*  staging = (int*)alloc((size_t)NBUCK * BCAP * 4);      // 4.8 MB
    float* as1    = (float*)alloc((size_t)NNODES * 4);
    float* ad1    = (float*)alloc((size_t)NNODES * 4);
    float* as2    = (float*)alloc((size_t)NNODES * 4);
    float* ad2    = (float*)alloc((size_t)NNODES * 4);
    int*   rowptr = (int*)alloc((size_t)(NNODES + 1) * 4);
    int*   esrc   = (int*)alloc((size_t)MEDGES * 4);
    ushort* W1p   = (ushort*)alloc((size_t)6 * 8 * 64 * 8 * 2); // 48 KiB
    ushort* W2p   = (ushort*)alloc((size_t)2 * 3 * 64 * 8 * 2); // 6 KiB
    int*   gcount = (int*)alloc((size_t)NBUCK * 4);
    uint32* h2b   = (uint32*)h1;  // h1 dead after agg96; 3.2 MB fits in 9.6 MB

    hipMemsetAsync(gcount, 0, (size_t)NBUCK * 4, stream);

    const int nbB1    = (MEDGES + 2047) / 2048;  // 416
    const int nbGemm  = (NNODES + 63) / 64;      // 782
    const int nbAgg96 = NNODES / 8;              // 6250 (exact)
    const int nbAgg32 = (NNODES + 3) / 4;        // 12500

    packw_kernel<<<13, 256, 0, stream>>>(W1, W2, W1p, W2p);
    bucket1_kernel<<<nbB1, 256, 0, stream>>>(ei, gcount, staging);
    bucket2_kernel<<<NBUCK, 256, 0, stream>>>(staging, gcount, rowptr, esrc);

    // layer 1
    gemm1_kernel<<<nbGemm, 256, 0, stream>>>(x, W1p, a1s, a1d, h1, as1, ad1);
    agg96_kernel<<<nbAgg96, 256, 0, stream>>>(h1, as1, ad1, b1, rowptr, esrc, out1b);

    // layer 2
    gemm2_kernel<<<nbGemm, 256, 0, stream>>>(out1b, W2p, a2s, a2d, h2b, as2, ad2);
    agg32_kernel<<<nbAgg32, 256, 0, stream>>>(h2b, as2, ad2, b2, rowptr, esrc, out);
}

// Round 11
// 205.072 us; speedup vs baseline: 1.1581x; 1.0487x over previous
//
#include <hip/hip_runtime.h>
#include <cstdint>
#include <cstddef>

#define NNODES 50000
#define NEDGES 800000
#define MEDGES (NEDGES + NNODES)
#define FIN    256
#define HID    96
#define NCLS   32
#define NEG_SLOPE 0.2f

#define NBUCK  391      // ceil(50000/128): 128-node dst ranges
#define BCAP   3072     // per-bucket staging capacity (mean 2176, sigma ~45)

typedef unsigned int uint32;
typedef __attribute__((ext_vector_type(8))) short short8;   // 8 bf16 = 4 VGPR
typedef __attribute__((ext_vector_type(4))) float f32x4;    // MFMA acc

__device__ __forceinline__ ushort bf_round(float f) {
    uint32 u = __float_as_uint(f);
    u += 0x7FFFu + ((u >> 16) & 1u);            // RNE
    return (ushort)(u >> 16);
}
__device__ __forceinline__ uint32 pack_bf16x2(float a, float b) {
    return (uint32)bf_round(a) | ((uint32)bf_round(b) << 16);
}
__device__ __forceinline__ float bf_lo(uint32 u) { return __uint_as_float(u << 16); }
__device__ __forceinline__ float bf_hi(uint32 u) { return __uint_as_float(u & 0xFFFF0000u); }
__device__ __forceinline__ float lrelu(float t) { return (t > 0.f) ? t : NEG_SLOPE * t; }
__device__ __forceinline__ float af(int i) { return __int_as_float(i); }
__device__ __forceinline__ float elu_fast(float t) { return (t > 0.f) ? t : (__expf(t) - 1.f); }

// ---------------- CSR build: bucketed two-pass sort ----------------
// staging entry packed: src (16 bits, 50000<65536) | (dst&127)<<16.

__global__ __launch_bounds__(256) void bucket1_kernel(const int* __restrict__ ei,
                                                      int* __restrict__ gcount,
                                                      int* __restrict__ staging) {
    __shared__ int hist[NBUCK];
    __shared__ int base_sh[NBUCK];
    for (int i = threadIdx.x; i < NBUCK; i += 256) hist[i] = 0;
    __syncthreads();

    int v[8], rk[8], bk[8];
    int e0 = blockIdx.x * 2048;
#pragma unroll
    for (int i = 0; i < 8; ++i) {
        int e = e0 + i * 256 + threadIdx.x;
        if (e < MEDGES) {
            int s, d;
            if (e < NEDGES) { s = ei[e]; d = ei[NEDGES + e]; }
            else            { s = e - NEDGES; d = s; }
            bk[i] = d >> 7;
            v[i]  = s | ((d & 127) << 16);
            rk[i] = atomicAdd(&hist[bk[i]], 1);
        } else bk[i] = -1;
    }
    __syncthreads();
    for (int i = threadIdx.x; i < NBUCK; i += 256) {
        int c = hist[i];
        base_sh[i] = c ? atomicAdd(&gcount[i], c) : 0;
    }
    __syncthreads();
#pragma unroll
    for (int i = 0; i < 8; ++i) {
        if (bk[i] >= 0) {
            int pos = base_sh[bk[i]] + rk[i];
            if (pos < BCAP)
                staging[(size_t)bk[i] * BCAP + pos] = v[i];
        }
    }
}

// One block per bucket. Self-scans gcount for its edge-space base, builds
// rowptr via LDS scan, writes esrc contiguously (L2-local lines).
__global__ __launch_bounds__(256) void bucket2_kernel(const int* __restrict__ staging,
                                                      const int* __restrict__ gcount,
                                                      int* __restrict__ rowptr,
                                                      int* __restrict__ esrc) {
    __shared__ int dcount[128];
    __shared__ int dincl[128];
    __shared__ int dexcl[128];
    __shared__ int fillc[128];
    __shared__ int red_s[256];

    const int b = blockIdx.x;
    const int t = threadIdx.x;

    int pv = 0;
    for (int idx = t; idx < b; idx += 256) pv += gcount[idx];
    red_s[t] = pv;
    __syncthreads();
    for (int off2 = 128; off2; off2 >>= 1) {
        if (t < off2) red_s[t] += red_s[t + off2];
        __syncthreads();
    }
    const int ebase = red_s[0];
    const int cnt   = gcount[b];
    const int node0 = b << 7;
    const int* st   = staging + (size_t)b * BCAP;

    for (int i = t; i < 128; i += 256) { dcount[i] = 0; fillc[i] = 0; }
    __syncthreads();

    for (int i = t; i < cnt; i += 256)
        atomicAdd(&dcount[st[i] >> 16], 1);
    __syncthreads();

    if (t < 128) dincl[t] = dcount[t];
    __syncthreads();
    for (int off = 1; off < 128; off <<= 1) {
        int val = (t >= off && t < 128) ? dincl[t - off] : 0;
        __syncthreads();
        if (t < 128) dincl[t] += val;
        __syncthreads();
    }
    if (t < 128) {
        int excl = dincl[t] - dcount[t];
        dexcl[t] = excl;
        int node = node0 + t;
        if (node < NNODES) rowptr[node] = ebase + excl;
    }
    if (b == NBUCK - 1 && t == 0) rowptr[NNODES] = MEDGES;
    __syncthreads();

    for (int i = t; i < cnt; i += 256) {
        int v = st[i];
        int dd = v >> 16;
        int r = atomicAdd(&fillc[dd], 1);
        esrc[ebase + dexcl[dd] + r] = v & 0xFFFF;
    }
}

// ---------------- W-pack (also zeroes gcount, replacing a memset dispatch) ----------------

__global__ __launch_bounds__(256) void packw_kernel(const float* __restrict__ W1,
                                                    const float* __restrict__ W2,
                                                    ushort* __restrict__ W1p,
                                                    ushort* __restrict__ W2p,
                                                    int* __restrict__ gcount) {
    int stride = gridDim.x * 256;
    for (int idx = blockIdx.x * 256 + threadIdx.x; idx < NBUCK; idx += stride)
        gcount[idx] = 0;
    for (int idx = blockIdx.x * 256 + threadIdx.x; idx < 6 * 8 * 64 * 8; idx += stride) {
        int j     = idx & 7;
        int lane  = (idx >> 3) & 63;
        int kstep = (idx >> 9) & 7;
        int ntile = idx >> 12;
        int k = kstep * 32 + ((lane >> 4) << 3) + j;
        int n = ntile * 16 + (lane & 15);
        W1p[idx] = bf_round(W1[(size_t)k * 96 + n]);
    }
    for (int idx = blockIdx.x * 256 + threadIdx.x; idx < 2 * 3 * 64 * 8; idx += stride) {
        int j     = idx & 7;
        int lane  = (idx >> 3) & 63;
        int kstep = (idx >> 9) % 3;
        int ntile = (idx >> 9) / 3;
        int k = kstep * 32 + ((lane >> 4) << 3) + j;
        int n = ntile * 16 + (lane & 15);
        W2p[idx] = bf_round(W2[(size_t)k * 32 + n]);
    }
}

// ---------------- GEMM1 via MFMA: h1(bf16) = x @ W1 (+ fused alpha dots) ----------------

__global__ __launch_bounds__(256) void gemm1_kernel(const float* __restrict__ x,
                                                    const ushort* __restrict__ W1p,
                                                    const float* __restrict__ a_src,
                                                    const float* __restrict__ a_dst,
                                                    ushort* __restrict__ h1,
                                                    float* __restrict__ as1,
                                                    float* __restrict__ ad1) {
    const int tid  = threadIdx.x;
    const int lane = tid & 63;
    const int wv   = tid >> 6;
    const int m    = lane & 15;
    const int quad = lane >> 4;
    const int node0 = blockIdx.x * 64;

    int arow = node0 + wv * 16 + m;
    if (arow >= NNODES) arow = NNODES - 1;
    const float* xr = x + (size_t)arow * FIN + quad * 8;

    const short8* Wp = (const short8*)W1p;

    f32x4 acc[6];
#pragma unroll
    for (int t = 0; t < 6; ++t) acc[t] = (f32x4){0.f, 0.f, 0.f, 0.f};

#pragma unroll
    for (int ks = 0; ks < 8; ++ks) {
        float4 v0 = *(const float4*)(xr + ks * 32);
        float4 v1 = *(const float4*)(xr + ks * 32 + 4);
        short8 a;
        a[0] = (short)bf_round(v0.x); a[1] = (short)bf_round(v0.y);
        a[2] = (short)bf_round(v0.z); a[3] = (short)bf_round(v0.w);
        a[4] = (short)bf_round(v1.x); a[5] = (short)bf_round(v1.y);
        a[6] = (short)bf_round(v1.z); a[7] = (short)bf_round(v1.w);
#pragma unroll
        for (int t = 0; t < 6; ++t) {
            short8 b = Wp[(t * 8 + ks) * 64 + lane];
            acc[t] = __builtin_amdgcn_mfma_f32_16x16x32_bf16(a, b, acc[t], 0, 0, 0);
        }
    }

    float as_reg[6], ad_reg[6];
#pragma unroll
    for (int t = 0; t < 6; ++t) {
        as_reg[t] = a_src[t * 16 + m];
        ad_reg[t] = a_dst[t * 16 + m];
    }

#pragma unroll
    for (int r = 0; r < 4; ++r) {
        int node = node0 + wv * 16 + quad * 4 + r;
        float ps = 0.f, pd = 0.f;
#pragma unroll
        for (int t = 0; t < 6; ++t) {
            ps += acc[t][r] * as_reg[t];
            pd += acc[t][r] * ad_reg[t];
        }
#pragma unroll
        for (int off = 1; off < 16; off <<= 1) {
            ps += __shfl_xor(ps, off);
            pd += __shfl_xor(pd, off);
        }
        if (node < NNODES) {
            ushort* hp = h1 + (size_t)node * 96 + m;
#pragma unroll
            for (int t = 0; t < 6; ++t) hp[t * 16] = bf_round(acc[t][r]);
            if (m == 0) { as1[node] = ps; ad1[node] = pd; }
        }
    }
}

// ---------------- GEMM2 via MFMA: h2(bf16 packed) = out1(bf16) @ W2 ----------------
// h2b[node*16 + m] packs (feat m, feat m+16) -> 64 B rows for agg32's gather.

__global__ __launch_bounds__(256) void gemm2_kernel(const uint32* __restrict__ y48,
                                                    const ushort* __restrict__ W2p,
                                                    const float* __restrict__ a_src,
                                                    const float* __restrict__ a_dst,
                                                    uint32* __restrict__ h2b,
                                                    float* __restrict__ as2,
                                                    float* __restrict__ ad2) {
    const int tid  = threadIdx.x;
    const int lane = tid & 63;
    const int wv   = tid >> 6;
    const int m    = lane & 15;
    const int quad = lane >> 4;
    const int node0 = blockIdx.x * 64;

    int arow = node0 + wv * 16 + m;
    if (arow >= NNODES) arow = NNODES - 1;
    const short8* Ar = (const short8*)(y48 + (size_t)arow * 48);
    const short8* Wp = (const short8*)W2p;

    f32x4 acc[2];
    acc[0] = (f32x4){0.f, 0.f, 0.f, 0.f};
    acc[1] = (f32x4){0.f, 0.f, 0.f, 0.f};

#pragma unroll
    for (int ks = 0; ks < 3; ++ks) {
        short8 a = Ar[ks * 4 + quad];
#pragma unroll
        for (int t = 0; t < 2; ++t) {
            short8 b = Wp[(t * 3 + ks) * 64 + lane];
            acc[t] = __builtin_amdgcn_mfma_f32_16x16x32_bf16(a, b, acc[t], 0, 0, 0);
        }
    }

    float as_reg[2], ad_reg[2];
#pragma unroll
    for (int t = 0; t < 2; ++t) {
        as_reg[t] = a_src[t * 16 + m];
        ad_reg[t] = a_dst[t * 16 + m];
    }

#pragma unroll
    for (int r = 0; r < 4; ++r) {
        int node = node0 + wv * 16 + quad * 4 + r;
        float ps = 0.f, pd = 0.f;
#pragma unroll
        for (int t = 0; t < 2; ++t) {
            ps += acc[t][r] * as_reg[t];
            pd += acc[t][r] * ad_reg[t];
        }
#pragma unroll
        for (int off = 1; off < 16; off <<= 1) {
            ps += __shfl_xor(ps, off);
            pd += __shfl_xor(pd, off);
        }
        if (node < NNODES) {
            h2b[(size_t)node * 16 + m] = pack_bf16x2(acc[0][r], acc[1][r]);
            if (m == 0) { as2[node] = ps; ad2[node] = pd; }
        }
    }
}

// ---------------- Fused attn + aggregation layer 1: TWO nodes per wave ----------------
// Half-wave (32 lanes) per node: 24 active lanes x uint2 = 192B row, lane owns
// 4 feats (no epilogue reduction). 2 independent edge streams -> 16 gathers in flight.

__global__ __launch_bounds__(256) void agg96_kernel(const ushort* __restrict__ h,
                                                    const float* __restrict__ asrc,
                                                    const float* __restrict__ adst,
                                                    const float* __restrict__ bias,
                                                    const int* __restrict__ rowptr,
                                                    const int* __restrict__ esrc,
                                                    uint32* __restrict__ out1b) {
    __shared__ int2 sa[4][2][32];
    const int wave = threadIdx.x >> 6;
    const int lane = threadIdx.x & 63;
    const int hf   = lane >> 5;
    const int fl32 = lane & 31;
    const int i = blockIdx.x * 8 + wave * 2 + hf;   // 50000 = 8*6250 exact

    const int start = rowptr[i];
    const int deg   = rowptr[i + 1] - start;
    const float ad  = adst[i];
    const int fl    = (fl32 < 24) ? fl32 : 23;

    float acc0 = 0.f, acc1 = 0.f, acc2 = 0.f, acc3 = 0.f;

    if (deg <= 32) {
        bool valid = fl32 < deg;
        int s_reg = valid ? esrc[start + fl32] : 0;
        float e = valid ? lrelu(asrc[s_reg] + ad) : -1e30f;
        float mx = e;
#pragma unroll
        for (int off = 16; off; off >>= 1) mx = fmaxf(mx, __shfl_xor(mx, off));
        float ex = valid ? __expf(e - mx) : 0.f;
        float sum = ex;
#pragma unroll
        for (int off = 16; off; off >>= 1) sum += __shfl_xor(sum, off);
        sa[wave][hf][fl32] = make_int2(s_reg, __float_as_int(ex / sum));

        const int4* sap = (const int4*)&sa[wave][hf][0];

        for (int eb = 0; eb < deg; eb += 8) {
            int4 qa = sap[(eb >> 1) + 0];
            int4 qb = sap[(eb >> 1) + 1];
            int4 qc = sap[(eb >> 1) + 2];
            int4 qd = sap[(eb >> 1) + 3];
            const uint2* r0 = (const uint2*)(h + (size_t)qa.x * 96);
            const uint2* r1 = (const uint2*)(h + (size_t)qa.z * 96);
            const uint2* r2 = (const uint2*)(h + (size_t)qb.x * 96);
            const uint2* r3 = (const uint2*)(h + (size_t)qb.z * 96);
            const uint2* r4 = (const uint2*)(h + (size_t)qc.x * 96);
            const uint2* r5 = (const uint2*)(h + (size_t)qc.z * 96);
            const uint2* r6 = (const uint2*)(h + (size_t)qd.x * 96);
            const uint2* r7 = (const uint2*)(h + (size_t)qd.z * 96);
            uint2 u0 = r0[fl], u1 = r1[fl], u2 = r2[fl], u3 = r3[fl];
            uint2 u4 = r4[fl], u5 = r5[fl], u6 = r6[fl], u7 = r7[fl];
            float a0 = af(qa.y), a1 = af(qa.w), a2 = af(qb.y), a3 = af(qb.w);
            float a4 = af(qc.y), a5 = af(qc.w), a6 = af(qd.y), a7 = af(qd.w);
            acc0 += a0 * bf_lo(u0.x) + a1 * bf_lo(u1.x) + a2 * bf_lo(u2.x) + a3 * bf_lo(u3.x)
                  + a4 * bf_lo(u4.x) + a5 * bf_lo(u5.x) + a6 * bf_lo(u6.x) + a7 * bf_lo(u7.x);
            acc1 += a0 * bf_hi(u0.x) + a1 * bf_hi(u1.x) + a2 * bf_hi(u2.x) + a3 * bf_hi(u3.x)
                  + a4 * bf_hi(u4.x) + a5 * bf_hi(u5.x) + a6 * bf_hi(u6.x) + a7 * bf_hi(u7.x);
            acc2 += a0 * bf_lo(u0.y) + a1 * bf_lo(u1.y) + a2 * bf_lo(u2.y) + a3 * bf_lo(u3.y)
                  + a4 * bf_lo(u4.y) + a5 * bf_lo(u5.y) + a6 * bf_lo(u6.y) + a7 * bf_lo(u7.y);
            acc3 += a0 * bf_hi(u0.y) + a1 * bf_hi(u1.y) + a2 * bf_hi(u2.y) + a3 * bf_hi(u3.y)
                  + a4 * bf_hi(u4.y) + a5 * bf_hi(u5.y) + a6 * bf_hi(u6.y) + a7 * bf_hi(u7.y);
        }
    } else {
        float mx = -1e30f;
        for (int p = start + fl32; p < start + deg; p += 32)
            mx = fmaxf(mx, lrelu(asrc[esrc[p]] + ad));
#pragma unroll
        for (int off = 16; off; off >>= 1) mx = fmaxf(mx, __shfl_xor(mx, off));
        float sum = 0.f;
        for (int p = start + fl32; p < start + deg; p += 32)
            sum += __expf(lrelu(asrc[esrc[p]] + ad) - mx);
#pragma unroll
        for (int off = 16; off; off >>= 1) sum += __shfl_xor(sum, off);
        float inv = 1.f / sum;
        for (int e = 0; e < deg; ++e) {
            int s = esrc[start + e];
            float a = __expf(lrelu(asrc[s] + ad) - mx) * inv;
            uint2 u = ((const uint2*)(h + (size_t)s * 96))[fl];
            acc0 += a * bf_lo(u.x);
            acc1 += a * bf_hi(u.x);
            acc2 += a * bf_lo(u.y);
            acc3 += a * bf_hi(u.y);
        }
    }

    if (fl32 < 24) {
        float v0 = elu_fast(acc0 + bias[4 * fl32 + 0]);
        float v1 = elu_fast(acc1 + bias[4 * fl32 + 1]);
        float v2 = elu_fast(acc2 + bias[4 * fl32 + 2]);
        float v3 = elu_fast(acc3 + bias[4 * fl32 + 3]);
        uint2 o;
        o.x = pack_bf16x2(v0, v1);
        o.y = pack_bf16x2(v2, v3);
        *(uint2*)(out1b + (size_t)i * 48 + 2 * fl32) = o;
    }
}

// ---------------- Fused attn + aggregation layer 2: TWO nodes per wave ----------------
// Half-wave per node; 4 groups x 8 lanes read 64 B h2b rows via dwordx2
// -> 8 edges per wave-VMEM-instruction across 2 independent streams.
// h2b uint32 index m holds feats (m, m+16).

__global__ __launch_bounds__(256) void agg32_kernel(const uint32* __restrict__ h2b,
                                                    const float* __restrict__ asrc,
                                                    const float* __restrict__ adst,
                                                    const float* __restrict__ bias,
                                                    const int* __restrict__ rowptr,
                                                    const int* __restrict__ esrc,
                                                    float* __restrict__ out) {
    __shared__ int2 sa[4][2][32];
    const int wave = threadIdx.x >> 6;
    const int lane = threadIdx.x & 63;
    const int hf   = lane >> 5;
    const int fl32 = lane & 31;
    const int i = blockIdx.x * 8 + wave * 2 + hf;   // 6250 blocks exact

    const int start = rowptr[i];
    const int deg   = rowptr[i + 1] - start;
    const float ad  = adst[i];
    const int g  = fl32 >> 3;        // edge group 0..3 within half
    const int fl = fl32 & 7;         // uint2 index within row

    float acc[4];
#pragma unroll
    for (int j = 0; j < 4; ++j) acc[j] = 0.f;

    if (deg <= 32) {
        bool valid = fl32 < deg;
        int s_reg = valid ? esrc[start + fl32] : 0;
        float e = valid ? lrelu(asrc[s_reg] + ad) : -1e30f;
        float mx = e;
#pragma unroll
        for (int off = 16; off; off >>= 1) mx = fmaxf(mx, __shfl_xor(mx, off));
        float ex = valid ? __expf(e - mx) : 0.f;
        float sum = ex;
#pragma unroll
        for (int off = 16; off; off >>= 1) sum += __shfl_xor(sum, off);
        sa[wave][hf][fl32] = make_int2(s_reg, __float_as_int(ex / sum));

#pragma unroll 2
        for (int eb = 0; eb < deg; eb += 4) {
            int e0 = eb + g;
            int2 q = sa[wave][hf][(e0 < 32) ? e0 : 31];
            float a = (e0 < deg) ? af(q.y) : 0.f;
            const uint2* hr = (const uint2*)(h2b + (size_t)q.x * 16);
            uint2 u = hr[fl];
            acc[0] = fmaf(a, bf_lo(u.x), acc[0]);   // feat 2fl
            acc[1] = fmaf(a, bf_hi(u.x), acc[1]);   // feat 2fl+16
            acc[2] = fmaf(a, bf_lo(u.y), acc[2]);   // feat 2fl+1
            acc[3] = fmaf(a, bf_hi(u.y), acc[3]);   // feat 2fl+17
        }
    } else {
        float mx = -1e30f;
        for (int p = start + fl32; p < start + deg; p += 32)
            mx = fmaxf(mx, lrelu(asrc[esrc[p]] + ad));
#pragma unroll
        for (int off = 16; off; off >>= 1) mx = fmaxf(mx, __shfl_xor(mx, off));
        float sum = 0.f;
        for (int p = start + fl32; p < start + deg; p += 32)
            sum += __expf(lrelu(asrc[esrc[p]] + ad) - mx);
#pragma unroll
        for (int off = 16; off; off >>= 1) sum += __shfl_xor(sum, off);
        float inv = 1.f / sum;
        for (int p = start + g; p < start + deg; p += 4) {
            int s = esrc[p];                          // 8 lanes same addr: broadcast
            float a = __expf(lrelu(asrc[s] + ad) - mx) * inv;
            const uint2* hr = (const uint2*)(h2b + (size_t)s * 16);
            uint2 u = hr[fl];
            acc[0] = fmaf(a, bf_lo(u.x), acc[0]);
            acc[1] = fmaf(a, bf_hi(u.x), acc[1]);
            acc[2] = fmaf(a, bf_lo(u.y), acc[2]);
            acc[3] = fmaf(a, bf_hi(u.y), acc[3]);
        }
    }

    // reduce over the 4 groups within the half
#pragma unroll
    for (int j = 0; j < 4; ++j) {
        acc[j] += __shfl_xor(acc[j], 8);
        acc[j] += __shfl_xor(acc[j], 16);
    }

    // log_softmax over 32 classes spread across lanes fl (8) x 4 values
    float z0 = acc[0] + bias[2 * fl];
    float z1 = acc[1] + bias[2 * fl + 16];
    float z2 = acc[2] + bias[2 * fl + 1];
    float z3 = acc[3] + bias[2 * fl + 17];
    float m2 = fmaxf(fmaxf(z0, z1), fmaxf(z2, z3));
#pragma unroll
    for (int off = 4; off; off >>= 1) m2 = fmaxf(m2, __shfl_xor(m2, off));
    float s2 = __expf(z0 - m2) + __expf(z1 - m2) + __expf(z2 - m2) + __expf(z3 - m2);
#pragma unroll
    for (int off = 4; off; off >>= 1) s2 += __shfl_xor(s2, off);
    float ls = m2 + __logf(s2);
    if (fl32 < 8) {
        float* op = out + (size_t)i * 32;
        op[2 * fl]      = z0 - ls;
        op[2 * fl + 16] = z1 - ls;
        op[2 * fl + 1]  = z2 - ls;
        op[2 * fl + 17] = z3 - ls;
    }
}

// ---------------- launch ----------------

extern "C" void kernel_launch(void* const* d_in, const int* in_sizes, int n_in,
                              void* d_out, int out_size, void* d_ws, size_t ws_size,
                              hipStream_t stream) {
    const float* x   = (const float*)d_in[0];
    const int*   ei  = (const int*)d_in[1];
    const float* W1  = (const float*)d_in[2];
    const float* a1s = (const float*)d_in[3];
    const float* a1d = (const float*)d_in[4];
    const float* b1  = (const float*)d_in[5];
    const float* W2  = (const float*)d_in[6];
    const float* a2s = (const float*)d_in[7];
    const float* a2d = (const float*)d_in[8];
    const float* b2  = (const float*)d_in[9];
    float* out = (float*)d_out;

    size_t off = 0;
    auto alloc = [&](size_t bytes) {
        void* p = (char*)d_ws + off;
        off += (bytes + 255) & ~(size_t)255;
        return p;
    };
    ushort* h1    = (ushort*)alloc((size_t)NNODES * HID * 2);   // bf16, 9.6 MB
    uint32* out1b = (uint32*)alloc((size_t)NNODES * 48 * 4);    // bf16x2, 9.6 MB
    int*  staging = (int*)alloc((size_t)NBUCK * BCAP * 4);      // 4.8 MB
    float* as1    = (float*)alloc((size_t)NNODES * 4);
    float* ad1    = (float*)alloc((size_t)NNODES * 4);
    float* as2    = (float*)alloc((size_t)NNODES * 4);
    float* ad2    = (float*)alloc((size_t)NNODES * 4);
    int*   rowptr = (int*)alloc((size_t)(NNODES + 1) * 4);
    int*   esrc   = (int*)alloc((size_t)MEDGES * 4);
    ushort* W1p   = (ushort*)alloc((size_t)6 * 8 * 64 * 8 * 2); // 48 KiB
    ushort* W2p   = (ushort*)alloc((size_t)2 * 3 * 64 * 8 * 2); // 6 KiB
    int*   gcount = (int*)alloc((size_t)NBUCK * 4);
    uint32* h2b   = (uint32*)h1;  // h1 dead after agg96; 3.2 MB fits in 9.6 MB

    const int nbB1    = (MEDGES + 2047) / 2048;  // 416
    const int nbGemm  = (NNODES + 63) / 64;      // 782
    const int nbAggP  = NNODES / 8;              // 6250 (exact)

    packw_kernel<<<13, 256, 0, stream>>>(W1, W2, W1p, W2p, gcount);
    bucket1_kernel<<<nbB1, 256, 0, stream>>>(ei, gcount, staging);
    bucket2_kernel<<<NBUCK, 256, 0, stream>>>(staging, gcount, rowptr, esrc);

    // layer 1
    gemm1_kernel<<<nbGemm, 256, 0, stream>>>(x, W1p, a1s, a1d, h1, as1, ad1);
    agg96_kernel<<<nbAggP, 256, 0, stream>>>(h1, as1, ad1, b1, rowptr, esrc, out1b);

    // layer 2
    gemm2_kernel<<<nbGemm, 256, 0, stream>>>(out1b, W2p, a2s, a2d, h2b, as2, ad2);
    agg32_kernel<<<nbAggP, 256, 0, stream>>>(h2b, as2, ad2, b2, rowptr, esrc, out);
}